// Round 2
// baseline (225.479 us; speedup 1.0000x reference)
//
#include <hip/hip_runtime.h>
#include <hip/hip_bf16.h>

typedef __attribute__((ext_vector_type(8))) short short8;
typedef __attribute__((ext_vector_type(4))) short short4v;
typedef __attribute__((ext_vector_type(4))) float f32x4;

#define NB      8
#define NSEQ    4096
#define NDIM    512
#define NHEADS  8
#define NDH     32
#define NINNER  256          // NHEADS*NDH
#define NCHUNK  32
#define TCH     128          // NSEQ / NCHUNK
#define MROWS   (NB*NSEQ)    // 32768

__device__ __forceinline__ short f2bf(float x) {
  union { float f; unsigned u; } v; v.f = x;
  unsigned r = (v.u + 0x7FFFu + ((v.u >> 16) & 1u)) >> 16;   // RNE
  return (short)(unsigned short)r;
}

__device__ __forceinline__ float sigmoidf_(float x) {
  return 1.0f / (1.0f + __expf(-x));
}

// ---------------------------------------------------------------------------
// bf16 MFMA GEMM: C[M,N] = A[M,K] @ B[K,N] + bias[N]   (A,B fp32 in, fp32 out)
// tiles: BM=BN=128, BK=32; 4 waves, each 64x64 via 4x4 16x16x32 frags
// ---------------------------------------------------------------------------
__global__ __launch_bounds__(256) void gemm_bf16_kernel(
    const float* __restrict__ A, const float* __restrict__ Bm,
    const float* __restrict__ bias, float* __restrict__ C,
    int M, int N, int K)
{
  constexpr int BM = 128, BN = 128, BK = 32, PAD = 8;
  __shared__ short As[BM][BK + PAD];       // [row][k]
  __shared__ short Bs[BN][BK + PAD];       // transposed: [n][k]

  const int tid = threadIdx.x;
  const int tiles_n = N / BN;
  const int bm = blockIdx.x / tiles_n;
  const int bn = blockIdx.x % tiles_n;
  const int wave = tid >> 6, lane = tid & 63;
  const int wm = wave >> 1, wn = wave & 1;        // 2x2 wave grid
  const int lr = lane & 15, lg = lane >> 4;

  f32x4 acc[4][4] = {};

  for (int kt = 0; kt < K; kt += BK) {
    // ---- stage A tile (128x32 fp32 -> bf16) ----
    #pragma unroll
    for (int i = 0; i < 4; ++i) {
      int idx = tid + i * 256;            // 0..1023
      int row = idx >> 3, kc = idx & 7;
      float4 v = *reinterpret_cast<const float4*>(
          &A[(size_t)(bm * BM + row) * K + kt + kc * 4]);
      short4v s = { f2bf(v.x), f2bf(v.y), f2bf(v.z), f2bf(v.w) };
      *reinterpret_cast<short4v*>(&As[row][kc * 4]) = s;
    }
    // ---- stage B tile transposed: Bs[n][k] = B[kt+k][bn*128+n] ----
    #pragma unroll
    for (int i = 0; i < 4; ++i) {
      int idx = tid + i * 256;            // 0..1023
      int kr = idx >> 5, nc = idx & 31;
      float4 v = *reinterpret_cast<const float4*>(
          &Bm[(size_t)(kt + kr) * N + bn * BN + nc * 4]);
      Bs[nc * 4 + 0][kr] = f2bf(v.x);
      Bs[nc * 4 + 1][kr] = f2bf(v.y);
      Bs[nc * 4 + 2][kr] = f2bf(v.z);
      Bs[nc * 4 + 3][kr] = f2bf(v.w);
    }
    __syncthreads();

    short8 af[4], bf[4];
    #pragma unroll
    for (int m = 0; m < 4; ++m)
      af[m] = *reinterpret_cast<const short8*>(&As[wm * 64 + m * 16 + lr][lg * 8]);
    #pragma unroll
    for (int n = 0; n < 4; ++n)
      bf[n] = *reinterpret_cast<const short8*>(&Bs[wn * 64 + n * 16 + lr][lg * 8]);

    #pragma unroll
    for (int m = 0; m < 4; ++m)
      #pragma unroll
      for (int n = 0; n < 4; ++n)
        acc[m][n] = __builtin_amdgcn_mfma_f32_16x16x32_bf16(
            af[m], bf[n], acc[m][n], 0, 0, 0);
    __syncthreads();
  }

  // ---- epilogue: +bias, fp32 store ----
  #pragma unroll
  for (int m = 0; m < 4; ++m) {
    int row0 = bm * BM + wm * 64 + m * 16 + lg * 4;
    #pragma unroll
    for (int n = 0; n < 4; ++n) {
      int col = bn * BN + wn * 64 + n * 16 + lr;
      float bv = bias[col];
      #pragma unroll
      for (int j = 0; j < 4; ++j)
        C[(size_t)(row0 + j) * N + col] = acc[m][n][j] + bv;
    }
  }
}

// ---------------------------------------------------------------------------
// Scan: y[t] = (1-a) y[t-1] + a (xp[t]-xp[t-1]),  y[-1]=xp[-1]=init[h,d]
// chunked: NCHUNK chunks of TCH per (b,h,d) channel. idx = ((b*H+h)*C+c)*D+d
// ---------------------------------------------------------------------------
__global__ void bnd_kernel(const float* __restrict__ xp,
                           const float* __restrict__ init_state,
                           float* __restrict__ bnd)
{
  int idx = blockIdx.x * 256 + threadIdx.x;            // 65536
  int d = idx & 31, c = (idx >> 5) & 31, h = (idx >> 10) & 7, b = idx >> 13;
  float v;
  if (c == 0) v = init_state[h * NDH + d];
  else        v = xp[((size_t)b * NSEQ + c * TCH - 1) * NINNER + h * NDH + d];
  bnd[idx] = v;
}

__global__ void scanA_kernel(float* __restrict__ xp,          // in-place -> l
                             const float* __restrict__ bnd,
                             const float* __restrict__ alpha_param,
                             float* __restrict__ Lfin)
{
  int idx = blockIdx.x * 256 + threadIdx.x;
  int d = idx & 31, c = (idx >> 5) & 31, h = (idx >> 10) & 7, b = idx >> 13;
  float a  = sigmoidf_(alpha_param[h]);
  float cc = 1.0f - a;
  float prev = bnd[idx];
  float y = 0.0f;
  size_t base = ((size_t)b * NSEQ + (size_t)c * TCH) * NINNER + h * NDH + d;
  for (int t0 = 0; t0 < TCH; t0 += 8) {
    float cur[8];
    #pragma unroll
    for (int i = 0; i < 8; ++i) cur[i] = xp[base + (size_t)(t0 + i) * NINNER];
    #pragma unroll
    for (int i = 0; i < 8; ++i) {
      y = cc * y + a * (cur[i] - prev);
      prev = cur[i];
      cur[i] = y;
    }
    #pragma unroll
    for (int i = 0; i < 8; ++i) xp[base + (size_t)(t0 + i) * NINNER] = cur[i];
  }
  Lfin[idx] = y;
}

__global__ void carry_kernel(const float* __restrict__ Lfin,
                             const float* __restrict__ init_state,
                             const float* __restrict__ alpha_param,
                             float* __restrict__ carry)
{
  int idx = blockIdx.x * 256 + threadIdx.x;            // 2048 (b,h,d)
  int d = idx & 31, h = (idx >> 5) & 7, b = idx >> 8;
  float a  = sigmoidf_(alpha_param[h]);
  float cc = 1.0f - a;
  float cT = powf(cc, (float)TCH);
  float cy = init_state[h * NDH + d];
  for (int c = 0; c < NCHUNK; ++c) {
    int j = ((b * NHEADS + h) * NCHUNK + c) * NDH + d;
    carry[j] = cy;
    cy = Lfin[j] + cT * cy;
  }
}

__global__ void scanC_kernel(float* __restrict__ y,           // in-place l -> y
                             const float* __restrict__ carry,
                             const float* __restrict__ alpha_param)
{
  int idx = blockIdx.x * 256 + threadIdx.x;
  int d = idx & 31, c = (idx >> 5) & 31, h = (idx >> 10) & 7, b = idx >> 13;
  float a  = sigmoidf_(alpha_param[h]);
  float cc = 1.0f - a;
  float cin = carry[idx];
  size_t base = ((size_t)b * NSEQ + (size_t)c * TCH) * NINNER + h * NDH + d;
  float pw = cc;
  for (int t0 = 0; t0 < TCH; t0 += 8) {
    float v[8];
    #pragma unroll
    for (int i = 0; i < 8; ++i) v[i] = y[base + (size_t)(t0 + i) * NINNER];
    #pragma unroll
    for (int i = 0; i < 8; ++i) { v[i] += pw * cin; pw *= cc; }
    #pragma unroll
    for (int i = 0; i < 8; ++i) y[base + (size_t)(t0 + i) * NINNER] = v[i];
  }
}

// ---------------------------------------------------------------------------
extern "C" void kernel_launch(void* const* d_in, const int* in_sizes, int n_in,
                              void* d_out, int out_size, void* d_ws, size_t ws_size,
                              hipStream_t stream)
{
  const float* x           = (const float*)d_in[0];
  const float* W_in        = (const float*)d_in[1];
  const float* b_in        = (const float*)d_in[2];
  const float* W_out       = (const float*)d_in[3];
  const float* b_out       = (const float*)d_in[4];
  const float* init_state  = (const float*)d_in[5];
  const float* alpha_param = (const float*)d_in[6];
  float* out = (float*)d_out;

  char* ws = (char*)d_ws;
  float* xp    = (float*)ws;                                   // 33554432 B
  float* bnd   = (float*)(ws + 33554432);                      // 262144 B
  float* Lfin  = (float*)(ws + 33554432 + 262144);             // 262144 B
  float* carry = (float*)(ws + 33554432 + 2 * 262144);         // 262144 B

  // GEMM1: xp = x @ W_in + b_in       (32768 x 256, K=512)
  gemm_bf16_kernel<<<(MROWS / 128) * (NINNER / 128), 256, 0, stream>>>(
      x, W_in, b_in, xp, MROWS, NINNER, NDIM);

  // chunked EMA scan (in-place over xp)
  bnd_kernel  <<<256, 256, 0, stream>>>(xp, init_state, bnd);
  scanA_kernel<<<256, 256, 0, stream>>>(xp, bnd, alpha_param, Lfin);
  carry_kernel<<<8,   256, 0, stream>>>(Lfin, init_state, alpha_param, carry);
  scanC_kernel<<<256, 256, 0, stream>>>(xp, carry, alpha_param);

  // GEMM2: out = y @ W_out + b_out    (32768 x 512, K=256)
  gemm_bf16_kernel<<<(MROWS / 128) * (NDIM / 128), 256, 0, stream>>>(
      xp, W_out, b_out, out, MROWS, NDIM, NINNER);
}

// Round 3
// 159.624 us; speedup vs baseline: 1.4126x; 1.4126x over previous
//
#include <hip/hip_runtime.h>
#include <hip/hip_bf16.h>

typedef __attribute__((ext_vector_type(8))) short short8;
typedef __attribute__((ext_vector_type(4))) short short4v;
typedef __attribute__((ext_vector_type(4))) float f32x4;

#define NB      8
#define NSEQ    4096
#define NDIM    512
#define NHEADS  8
#define NDH     32
#define NINNER  256          // NHEADS*NDH
#define NCHUNK  32
#define TCH     128          // NSEQ / NCHUNK == BM
#define MROWS   (NB*NSEQ)    // 32768

__device__ __forceinline__ short f2bf(float x) {
  union { float f; unsigned u; } v; v.f = x;
  unsigned r = (v.u + 0x7FFFu + ((v.u >> 16) & 1u)) >> 16;   // RNE
  return (short)(unsigned short)r;
}
__device__ __forceinline__ float bf2f(short s) {
  union { unsigned u; float f; } v; v.u = ((unsigned)(unsigned short)s) << 16;
  return v.f;
}
__device__ __forceinline__ float sigmoidf_(float x) {
  return 1.0f / (1.0f + expf(-x));
}

// ---------------------------------------------------------------------------
// W converter: out[n][k] = bf16(in[k][n])  (transpose + convert, 32x32 tiles)
// ---------------------------------------------------------------------------
__global__ __launch_bounds__(256) void wconv_kernel(
    const float* __restrict__ in, short* __restrict__ out, int K, int N)
{
  __shared__ short T[32][33];
  const int tiles_n = N >> 5;
  const int ki = blockIdx.x / tiles_n, ni = blockIdx.x % tiles_n;
  const int tx = threadIdx.x & 31, ty0 = threadIdx.x >> 5;
  #pragma unroll
  for (int r = 0; r < 4; ++r) {
    int ty = ty0 + r * 8;
    T[ty][tx] = f2bf(in[(size_t)(ki * 32 + ty) * N + ni * 32 + tx]);
  }
  __syncthreads();
  #pragma unroll
  for (int r = 0; r < 4; ++r) {
    int ty = ty0 + r * 8;
    out[(size_t)(ni * 32 + ty) * K + ki * 32 + tx] = T[tx][ty];
  }
}

// ---------------------------------------------------------------------------
// Kernel 1: GEMM1 (xp = x @ W_in + b_in) fused with local EMA-sum scan.
//   BM=128(=chunk) BN=128 BK=64. 4 waves (2x2), 16x16x32 bf16 MFMA.
//   Epilogue: tile -> LDS fp32 X[128][132]; per-column scan
//     u[tau] = a*xp[tau] - a^2*Eloc[tau-1];  Eloc[tau] = cc*Eloc[tau-1]+xp[tau]
//   writes u (bf16) and Eloc[127] -> Lfin.
//   Dynamic LDS: union { As[128][72]+Bs[128][72] bf16 | X[128][132] f32 } = 67584B
// ---------------------------------------------------------------------------
__global__ __launch_bounds__(256) void gemm1_scan_kernel(
    const float* __restrict__ x, const short* __restrict__ WinT,
    const float* __restrict__ b_in, const float* __restrict__ alpha_param,
    short* __restrict__ u, float* __restrict__ Lfin)
{
  constexpr int K = NDIM, BK = 64;
  extern __shared__ char smem[];
  short (*As)[72] = reinterpret_cast<short(*)[72]>(smem);
  short (*Bs)[72] = reinterpret_cast<short(*)[72]>(smem + 128 * 72 * 2);
  float (*X)[132] = reinterpret_cast<float(*)[132]>(smem);

  const int tid = threadIdx.x;
  // XCD-bijective swizzle (nwg=512, 512%8==0): consecutive tiles on same XCD
  const int nwg = gridDim.x;
  const int tile = (blockIdx.x % 8) * (nwg / 8) + blockIdx.x / 8;
  const int bm = tile >> 1;          // tiles_n = 2
  const int bn = tile & 1;
  const int wave = tid >> 6, lane = tid & 63;
  const int wm = wave >> 1, wn = wave & 1;
  const int lr = lane & 15, lg = lane >> 4;

  f32x4 acc[4][4] = {};

  for (int kt = 0; kt < K; kt += BK) {
    // stage A: x fp32 -> bf16, 8 elems/thread/rep
    #pragma unroll
    for (int i = 0; i < 4; ++i) {
      int idx = tid + i * 256;                 // 0..1023
      int row = idx >> 3, k8 = idx & 7;
      const float4* src = reinterpret_cast<const float4*>(
          &x[(size_t)(bm * 128 + row) * K + kt + k8 * 8]);
      float4 v0 = src[0], v1 = src[1];
      short8 s;
      s[0] = f2bf(v0.x); s[1] = f2bf(v0.y); s[2] = f2bf(v0.z); s[3] = f2bf(v0.w);
      s[4] = f2bf(v1.x); s[5] = f2bf(v1.y); s[6] = f2bf(v1.z); s[7] = f2bf(v1.w);
      *reinterpret_cast<short8*>(&As[row][k8 * 8]) = s;
    }
    // stage B: pre-converted bf16 [n][k], straight vector copy
    #pragma unroll
    for (int i = 0; i < 4; ++i) {
      int idx = tid + i * 256;
      int n = idx >> 3, k8 = idx & 7;
      *reinterpret_cast<short8*>(&Bs[n][k8 * 8]) =
          *reinterpret_cast<const short8*>(&WinT[(size_t)(bn * 128 + n) * K + kt + k8 * 8]);
    }
    __syncthreads();
    #pragma unroll
    for (int ks = 0; ks < 2; ++ks) {
      short8 af[4], bf[4];
      #pragma unroll
      for (int m = 0; m < 4; ++m)
        af[m] = *reinterpret_cast<const short8*>(&As[wm * 64 + m * 16 + lr][ks * 32 + lg * 8]);
      #pragma unroll
      for (int n = 0; n < 4; ++n)
        bf[n] = *reinterpret_cast<const short8*>(&Bs[wn * 64 + n * 16 + lr][ks * 32 + lg * 8]);
      #pragma unroll
      for (int m = 0; m < 4; ++m)
        #pragma unroll
        for (int n = 0; n < 4; ++n)
          acc[m][n] = __builtin_amdgcn_mfma_f32_16x16x32_bf16(af[m], bf[n], acc[m][n], 0, 0, 0);
    }
    __syncthreads();
  }

  // epilogue: acc + bias -> LDS X (fp32)
  #pragma unroll
  for (int m = 0; m < 4; ++m) {
    int r0 = wm * 64 + m * 16 + lg * 4;
    #pragma unroll
    for (int n = 0; n < 4; ++n) {
      int cl = wn * 64 + n * 16 + lr;
      float bv = b_in[bn * 128 + cl];
      #pragma unroll
      for (int j = 0; j < 4; ++j) X[r0 + j][cl] = acc[m][n][j] + bv;
    }
  }
  __syncthreads();

  // per-column local scan (threads 0..127), batch-8 to hide LDS latency
  if (tid < 128) {
    int col = bn * 128 + tid;
    float a = sigmoidf_(alpha_param[col >> 5]);
    float cc = 1.0f - a, a2 = a * a;
    float E = 0.0f;
    for (int t0 = 0; t0 < 128; t0 += 8) {
      float xv[8], uu[8];
      #pragma unroll
      for (int i = 0; i < 8; ++i) xv[i] = X[t0 + i][tid];
      #pragma unroll
      for (int i = 0; i < 8; ++i) {
        uu[i] = fmaf(-a2, E, a * xv[i]);
        E = fmaf(cc, E, xv[i]);
      }
      #pragma unroll
      for (int i = 0; i < 8; ++i) X[t0 + i][tid] = uu[i];
    }
    Lfin[bm * 256 + col] = E;
  }
  __syncthreads();

  // coalesced u write (bf16)
  #pragma unroll
  for (int i = 0; i < 16; ++i) {
    int e = tid + i * 256;                     // float4 units, 0..4095
    int r = e >> 5, c4 = e & 31;
    float4 v = *reinterpret_cast<const float4*>(&X[r][c4 * 4]);
    short4v s = { f2bf(v.x), f2bf(v.y), f2bf(v.z), f2bf(v.w) };
    *reinterpret_cast<short4v*>(&u[(size_t)(bm * 128 + r) * NINNER + bn * 128 + c4 * 4]) = s;
  }
}

// ---------------------------------------------------------------------------
// Kernel 2: chunk-carry scan + G + ccpow table.
//   C_0 = 0;  G_c = -a^2*C_c + (cc-a)*cc^{128c}*init;  C_{c+1} = Eloc_c + cc^128*C_c
//   ccpow[h][tau] = cc_h^tau  (8x128)
// ---------------------------------------------------------------------------
__global__ void carry_kernel(const float* __restrict__ Lfin,
                             const float* __restrict__ init_state,
                             const float* __restrict__ alpha_param,
                             float* __restrict__ G, float* __restrict__ ccpow)
{
  int gid = blockIdx.x * 256 + threadIdx.x;
  if (blockIdx.x < 8) {                        // 2048 (b,h,d) carries
    int col = gid & 255, b = gid >> 8;
    float a = sigmoidf_(alpha_param[col >> 5]);
    float cc = 1.0f - a, a2 = a * a;
    float cT = powf(cc, 128.0f);
    float C = 0.0f, ccp = 1.0f;
    float d0 = (cc - a) * init_state[col];
    for (int c = 0; c < NCHUNK; ++c) {
      int bm = b * NCHUNK + c;
      G[bm * 256 + col] = fmaf(-a2, C, d0 * ccp);
      C = fmaf(cT, C, Lfin[bm * 256 + col]);
      ccp *= cT;
    }
  } else {                                     // 1024 ccpow entries
    int idx = gid - 2048;
    int h = idx >> 7, t = idx & 127;
    float a = sigmoidf_(alpha_param[h]);
    ccpow[idx] = powf(1.0f - a, (float)t);
  }
}

// ---------------------------------------------------------------------------
// Kernel 3: GEMM2 (out = o @ W_out + b_out) with carry injection in A-staging:
//   o[row,k] = u[row,k] + ccpow[h(k)][row&127] * G[(row>>7)*256 + k]
// ---------------------------------------------------------------------------
__global__ __launch_bounds__(256) void gemm2_kernel(
    const short* __restrict__ u, const short* __restrict__ WoutT,
    const float* __restrict__ G, const float* __restrict__ ccpow,
    const float* __restrict__ b_out, float* __restrict__ out)
{
  constexpr int K = NINNER, BK = 64, NOUT = NDIM;
  __shared__ short As[128][72];
  __shared__ short Bs[128][72];
  __shared__ float Gs[256];
  __shared__ float Ps[1024];

  const int tid = threadIdx.x;
  const int nwg = gridDim.x;                   // 1024, %8==0
  const int tile = (blockIdx.x % 8) * (nwg / 8) + blockIdx.x / 8;
  const int bm = tile >> 2;                    // tiles_n = 4
  const int bn = tile & 3;
  const int wave = tid >> 6, lane = tid & 63;
  const int wm = wave >> 1, wn = wave & 1;
  const int lr = lane & 15, lg = lane >> 4;

  Gs[tid] = G[bm * 256 + tid];
  #pragma unroll
  for (int i = 0; i < 4; ++i) Ps[tid + i * 256] = ccpow[tid + i * 256];
  __syncthreads();

  f32x4 acc[4][4] = {};

  for (int kt = 0; kt < K; kt += BK) {
    // stage A: u bf16 + delta -> bf16
    #pragma unroll
    for (int i = 0; i < 4; ++i) {
      int idx = tid + i * 256;
      int row = idx >> 3, k8 = idx & 7;
      int kc = kt + k8 * 8;
      short8 uv = *reinterpret_cast<const short8*>(&u[(size_t)(bm * 128 + row) * K + kc]);
      float ccp = Ps[(kc >> 5) * 128 + row];
      short8 s;
      #pragma unroll
      for (int j = 0; j < 8; ++j)
        s[j] = f2bf(fmaf(ccp, Gs[kc + j], bf2f(uv[j])));
      *reinterpret_cast<short8*>(&As[row][k8 * 8]) = s;
    }
    // stage B
    #pragma unroll
    for (int i = 0; i < 4; ++i) {
      int idx = tid + i * 256;
      int n = idx >> 3, k8 = idx & 7;
      *reinterpret_cast<short8*>(&Bs[n][k8 * 8]) =
          *reinterpret_cast<const short8*>(&WoutT[(size_t)(bn * 128 + n) * K + kt + k8 * 8]);
    }
    __syncthreads();
    #pragma unroll
    for (int ks = 0; ks < 2; ++ks) {
      short8 af[4], bf[4];
      #pragma unroll
      for (int m = 0; m < 4; ++m)
        af[m] = *reinterpret_cast<const short8*>(&As[wm * 64 + m * 16 + lr][ks * 32 + lg * 8]);
      #pragma unroll
      for (int n = 0; n < 4; ++n)
        bf[n] = *reinterpret_cast<const short8*>(&Bs[wn * 64 + n * 16 + lr][ks * 32 + lg * 8]);
      #pragma unroll
      for (int m = 0; m < 4; ++m)
        #pragma unroll
        for (int n = 0; n < 4; ++n)
          acc[m][n] = __builtin_amdgcn_mfma_f32_16x16x32_bf16(af[m], bf[n], acc[m][n], 0, 0, 0);
    }
    __syncthreads();
  }

  #pragma unroll
  for (int m = 0; m < 4; ++m) {
    int row0 = bm * 128 + wm * 64 + m * 16 + lg * 4;
    #pragma unroll
    for (int n = 0; n < 4; ++n) {
      int col = bn * 128 + wn * 64 + n * 16 + lr;
      float bv = b_out[col];
      #pragma unroll
      for (int j = 0; j < 4; ++j)
        out[(size_t)(row0 + j) * NOUT + col] = acc[m][n][j] + bv;
    }
  }
}

// ---------------------------------------------------------------------------
extern "C" void kernel_launch(void* const* d_in, const int* in_sizes, int n_in,
                              void* d_out, int out_size, void* d_ws, size_t ws_size,
                              hipStream_t stream)
{
  const float* x           = (const float*)d_in[0];
  const float* W_in        = (const float*)d_in[1];
  const float* b_in        = (const float*)d_in[2];
  const float* W_out       = (const float*)d_in[3];
  const float* b_out       = (const float*)d_in[4];
  const float* init_state  = (const float*)d_in[5];
  const float* alpha_param = (const float*)d_in[6];
  float* out = (float*)d_out;

  char* ws = (char*)d_ws;
  short* u      = (short*)ws;                          // 16777216 B (bf16)
  float* Lfin   = (float*)(ws + 16777216);             // 262144 B
  float* G      = (float*)(ws + 16777216 + 262144);    // 262144 B
  float* ccpow  = (float*)(ws + 16777216 + 2*262144);  // 4096 B (pad to 8192)
  short* WinT   = (short*)(ws + 16777216 + 2*262144 + 8192);            // 262144 B
  short* WoutT  = (short*)(ws + 16777216 + 2*262144 + 8192 + 262144);   // 262144 B

  // W_in (512x256) -> WinT [256][512] bf16; W_out (256x512) -> WoutT [512][256]
  wconv_kernel<<<(NDIM/32)*(NINNER/32), 256, 0, stream>>>(W_in, WinT, NDIM, NINNER);
  wconv_kernel<<<(NINNER/32)*(NDIM/32), 256, 0, stream>>>(W_out, WoutT, NINNER, NDIM);

  // GEMM1 + local scan  (grid 512 = 256 bm x 2 bn)
  gemm1_scan_kernel<<<(MROWS/128)*(NINNER/128), 256, 67584, stream>>>(
      x, WinT, b_in, alpha_param, u, Lfin);

  // chunk carries + G + ccpow
  carry_kernel<<<12, 256, 0, stream>>>(Lfin, init_state, alpha_param, G, ccpow);

  // GEMM2 + carry injection  (grid 1024 = 256 bm x 4 bn)
  gemm2_kernel<<<(MROWS/128)*(NDIM/128), 256, 0, stream>>>(
      u, WoutT, G, ccpow, b_out, out);
}